// Round 6
// baseline (218.370 us; speedup 1.0000x reference)
//
#include <hip/hip_runtime.h>
#include <hip/hip_bf16.h>

#define N_NODES   4096
#define E_EDGES   262144
#define IN_DIM    256
#define EDGE_DIM  16
#define NAF       16
#define LATENT    128
#define NBT       5

#define LATENT_OFF 0
#define ATOMS_OFF  (N_NODES * LATENT)                 // 524288
#define BONDS_OFF  (ATOMS_OFF + N_NODES * NAF)        // 589824

// hash table: 2^20 u64 slots = 8 MB, load factor 0.25
#define TBITS 20
#define TSIZE (1u << TBITS)
#define TMASK (TSIZE - 1u)

typedef float    f32x4  __attribute__((ext_vector_type(4)));
typedef float    f32x4v __attribute__((ext_vector_type(4)));
typedef short    bf16x8 __attribute__((ext_vector_type(8)));
typedef unsigned u32x2  __attribute__((ext_vector_type(2)));
typedef unsigned u32x4  __attribute__((ext_vector_type(4)));

// silu via v_rcp_f32 (accuracy validated in R1: absmax unchanged)
__device__ __forceinline__ float silu_f(float x) {
    return x * __builtin_amdgcn_rcpf(1.0f + __expf(-x));
}

__device__ __forceinline__ unsigned pack_bf16x2(float lo, float hi) {
#if __has_builtin(__builtin_amdgcn_cvt_pk_bf16_f32)
    typedef __bf16 bf16x2_t __attribute__((ext_vector_type(2)));
    union { bf16x2_t v; unsigned u; } c;
    c.v = __builtin_amdgcn_cvt_pk_bf16_f32(lo, hi);
    return c.u;
#else
    union { float f; unsigned u; } a, b;
    a.f = lo; b.f = hi;
    const unsigned ra = (a.u + 0x7FFFu + ((a.u >> 16) & 1u)) >> 16;
    const unsigned rb = (b.u + 0x7FFFu + ((b.u >> 16) & 1u)) >> 16;
    return ra | (rb << 16);
#endif
}

__device__ __forceinline__ float bf_lo(unsigned u) {
    union { unsigned x; float f; } c; c.x = u << 16; return c.f;
}
__device__ __forceinline__ float bf_hi(unsigned u) {
    union { unsigned x; float f; } c; c.x = u & 0xFFFF0000u; return c.f;
}

// split fp32x8 into bf16 hi + bf16 lo fragments (x = hi + lo exactly to 2^-18)
__device__ __forceinline__ void split_bf16(const float4 x0, const float4 x1,
                                           bf16x8* hi, bf16x8* lo) {
    union { bf16x8 v; unsigned u[4]; } H, L;
    H.u[0] = pack_bf16x2(x0.x, x0.y);
    H.u[1] = pack_bf16x2(x0.z, x0.w);
    H.u[2] = pack_bf16x2(x1.x, x1.y);
    H.u[3] = pack_bf16x2(x1.z, x1.w);
    L.u[0] = pack_bf16x2(x0.x - bf_lo(H.u[0]), x0.y - bf_hi(H.u[0]));
    L.u[1] = pack_bf16x2(x0.z - bf_lo(H.u[1]), x0.w - bf_hi(H.u[1]));
    L.u[2] = pack_bf16x2(x1.x - bf_lo(H.u[2]), x1.y - bf_hi(H.u[2]));
    L.u[3] = pack_bf16x2(x1.z - bf_lo(H.u[3]), x1.w - bf_hi(H.u[3]));
    *hi = H.v; *lo = L.v;
}

// async gather: per-lane 16B global -> LDS[uniform base + lane*16]
__device__ __forceinline__ void gld_lds16(const void* g, void* l) {
    __builtin_amdgcn_global_load_lds(
        (const __attribute__((address_space(1))) unsigned*)g,
        (__attribute__((address_space(3))) unsigned*)l, 16, 0, 0);
}

__device__ __forceinline__ unsigned hashh(unsigned key) {
    return (key * 2654435761u) >> (32 - TBITS);
}

// 2-slot speculative resolve (R5, validated). Slow-path loads are dynamic but
// never counted in any vmcnt N -> only ever make counted waits stricter.
__device__ __forceinline__ int resolve2(const unsigned long long* __restrict__ tab,
                                        unsigned key, unsigned long long s0,
                                        unsigned long long s1, unsigned h) {
    if ((unsigned)(s0 >> 18) == key + 1u) return (int)(s0 & 0x3FFFFu);
    if (s0 == 0ULL) return -1;
    if ((unsigned)(s1 >> 18) == key + 1u) return (int)(s1 & 0x3FFFFu);
    if (s1 == 0ULL) return -1;
    h = (h + 2u) & TMASK;
    while (true) {
        const unsigned long long cur = tab[h];
        if (cur == 0ULL) return -1;
        if ((unsigned)(cur >> 18) == key + 1u) return (int)(cur & 0x3FFFFu);
        h = (h + 1u) & TMASK;
    }
}

// ---------------------------------------------------------------------------
// k_front: blocks 0..1023  : GEMM1
//          blocks 1024..2047: hash insert (direct-CAS: no pre-read RT)
//          block  2048      : prepack A1pre/A2pre
// ---------------------------------------------------------------------------
__global__ __launch_bounds__(256) void k_front(const float* __restrict__ s,
                                               const float* __restrict__ Wsh,
                                               const float* __restrict__ bsh,
                                               const int* __restrict__ eidx,
                                               const float* __restrict__ Wb,
                                               const float* __restrict__ bb,
                                               const float* __restrict__ Wbs,
                                               unsigned short* __restrict__ sact16,
                                               unsigned long long* __restrict__ tab,
                                               u32x4* __restrict__ A1pre,
                                               u32x4* __restrict__ A2pre) {
    const int blk = blockIdx.x;
    const int c   = threadIdx.x;

    if (blk >= 1024) {
        if (blk < 2048) {
            // ---- hash insert (winner = max edge id per key), direct CAS
            const int k = (blk - 1024) * 256 + c;
            const unsigned j = (unsigned)eidx[k];
            const unsigned i = (unsigned)eidx[E_EDGES + k];
            const unsigned key = (j << 12) | i;
            const unsigned long long mine =
                ((unsigned long long)(key + 1u) << 18) | (unsigned)k;
            unsigned h = hashh(key);
            while (true) {
                const unsigned long long old = atomicCAS(&tab[h], 0ULL, mine);
                if (old == 0ULL) return;                    // claimed empty slot
                if ((unsigned)(old >> 18) == key + 1u) {    // key already present
                    atomicMax(&tab[h], mine);
                    return;
                }
                h = (h + 1u) & TMASK;
            }
        } else {
            // ---- prepack: A1 = {Wb pair x2, pk(bb,0), 0}; A2 = {Wbs pair x2, 0, 0}
#pragma unroll
            for (int ee = 0; ee < 4; ++ee) {
                const int idx  = c + 256 * ee;
                const int g    = idx >> 6;
                const int lane = idx & 63;
                const int mm   = lane & 15;
                const int qq   = lane >> 4;

                const float4 w = *(const float4*)(Wb + (16 * g + mm) * EDGE_DIM + 4 * qq);
                u32x4 r1;
                r1.x = pack_bf16x2(w.x, w.y);
                r1.y = pack_bf16x2(w.z, w.w);
                r1.z = pack_bf16x2(bb[16 * g + mm], 0.0f);
                r1.w = 0u;
                A1pre[idx] = r1;

                u32x4 r2;
                if (mm < NBT) {
                    const float4 ws = *(const float4*)(Wbs + mm * IN_DIM + 16 * g + 4 * qq);
                    r2.x = pack_bf16x2(ws.x, ws.y);
                    r2.y = pack_bf16x2(ws.z, ws.w);
                } else {
                    r2.x = 0u; r2.y = 0u;
                }
                r2.z = 0u; r2.w = 0u;
                A2pre[idx] = r2;
            }
        }
        return;
    }

    // ---- GEMM1 tile: wave -> (row_tile, col_tile); 256 x 16 tiles
    const int lane = c & 63;
    const int wv   = c >> 6;
    const int wave = blk * 4 + wv;
    const int m    = lane & 15;
    const int q    = lane >> 4;
    const int row0 = (wave >> 4) * 16;
    const int col0 = (wave & 15) * 16;

    f32x4v acc;
    {
        const float bias = bsh[col0 + m];
        acc[0] = bias; acc[1] = bias; acc[2] = bias; acc[3] = bias;
    }

    const float* ap = s   + (size_t)(row0 + m) * IN_DIM + 8 * q;
    const float* bp = Wsh + (size_t)(col0 + m) * IN_DIM + 8 * q;

#pragma unroll
    for (int c8 = 0; c8 < 8; ++c8) {
        const float4 a0 = *(const float4*)(ap + 32 * c8);
        const float4 a1 = *(const float4*)(ap + 32 * c8 + 4);
        const float4 b0 = *(const float4*)(bp + 32 * c8);
        const float4 b1 = *(const float4*)(bp + 32 * c8 + 4);
        bf16x8 Ah, Al, Bh, Bl;
        split_bf16(a0, a1, &Ah, &Al);
        split_bf16(b0, b1, &Bh, &Bl);
        acc = __builtin_amdgcn_mfma_f32_16x16x32_bf16(Ah, Bh, acc, 0, 0, 0);
        acc = __builtin_amdgcn_mfma_f32_16x16x32_bf16(Al, Bh, acc, 0, 0, 0);
        acc = __builtin_amdgcn_mfma_f32_16x16x32_bf16(Ah, Bl, acc, 0, 0, 0);
    }

#pragma unroll
    for (int r = 0; r < 4; ++r) {
        const int row = row0 + 4 * q + r;
        const float v = silu_f(acc[r]);
        sact16[(size_t)row * IN_DIM + col0 + m] =
            (unsigned short)(pack_bf16x2(v, 0.0f) & 0xFFFFu);
    }
}

// fence helpers. Counted-wait safety rule (R3 post-mortem, R4/R5 validated):
// vmcnt(N) targeting cluster X requires N <= #STATICALLY-issued loads younger
// than X. Dynamic loads (hash slow path) are legal anywhere but NEVER counted
// -> FIFO retirement means they only make waits stricter.
#define SB0()    __builtin_amdgcn_sched_barrier(0)
#define LGKM0()  do { __asm__ __volatile__("s_waitcnt lgkmcnt(0)" ::: "memory"); SB0(); } while (0)
#define VMW(n)   do { __asm__ __volatile__("s_waitcnt vmcnt(" #n ")" ::: "memory"); SB0(); } while (0)

// ---------------------------------------------------------------------------
// k_edges_mfma: blocks 0..2047  : edge tiles, 2 tiles/wave (A,B), quarter-
//                                 staged X/Y double buffer; tile B's entire
//                                 front chain (tab, resolve, e) hides under
//                                 tile A's compute (R6 2-tile pipeline)
//               blocks 2048..2623: GEMM2 — atoms/latent = sact16@Wa^T + ba
// LDS: 8 KB/wave = 2 x 4 KB quarter-buffers -> 32 KB/block, 5 blocks/CU.
// ---------------------------------------------------------------------------
__global__ __launch_bounds__(256, 5) void k_edges_mfma(const int* __restrict__ eidx,
                                                       const float* __restrict__ e,
                                                       const unsigned long long* __restrict__ tab,
                                                       const unsigned short* __restrict__ sact16,
                                                       const u32x4* __restrict__ A1pre,
                                                       const u32x4* __restrict__ A2pre,
                                                       const float* __restrict__ bbs,
                                                       const float* __restrict__ Wa,
                                                       const float* __restrict__ ba,
                                                       float* __restrict__ out) {
    __shared__ unsigned lds_all[4][2048];   // 8 KB/wave
    const int blk  = blockIdx.x;
    const int lane = threadIdx.x & 63;
    const int wv   = threadIdx.x >> 6;
    const int m    = lane & 15;
    const int q    = lane >> 4;

    if (blk >= 2048) {
        // ---- GEMM2: wave -> (row_tile, col_tile) over 256 x 9 tiles
        const int wave = (blk - 2048) * 4 + wv;   // 0..2303
        const int rt = wave / 9;
        const int ct = wave - rt * 9;
        const int row0  = rt * 16;
        const int n_abs = ct * 16 + m;            // 0..143

        f32x4v acc;
        {
            const float bias = ba[n_abs];
            acc[0] = bias; acc[1] = bias; acc[2] = bias; acc[3] = bias;
        }

        const unsigned short* apu = sact16 + (size_t)(row0 + m) * IN_DIM + 8 * q;
        const float*          bp  = Wa + (size_t)n_abs * IN_DIM + 8 * q;

#pragma unroll
        for (int c8 = 0; c8 < 8; ++c8) {
            const bf16x8 A = *(const bf16x8*)(apu + 32 * c8);
            const float4 b0 = *(const float4*)(bp + 32 * c8);
            const float4 b1 = *(const float4*)(bp + 32 * c8 + 4);
            bf16x8 Bh, Bl;
            split_bf16(b0, b1, &Bh, &Bl);
            acc = __builtin_amdgcn_mfma_f32_16x16x32_bf16(A, Bh, acc, 0, 0, 0);
            acc = __builtin_amdgcn_mfma_f32_16x16x32_bf16(A, Bl, acc, 0, 0, 0);
        }
#pragma unroll
        for (int r = 0; r < 4; ++r) {
            const int row = row0 + 4 * q + r;
            if (n_abs < NAF)
                out[ATOMS_OFF + (size_t)row * NAF + n_abs] = acc[r];
            else
                out[LATENT_OFF + (size_t)row * LATENT + (n_abs - NAF)] = acc[r];
        }
        return;
    }

    // ---- edge path: this wave owns tiles ka = wave*32, kb = ka+16
    const int wave = blk * 4 + wv;
    const int ka   = __builtin_amdgcn_readfirstlane(wave * 32);
    const int kb   = ka + 16;
    unsigned* myl  = lds_all[wv];
    const short one_q0 = (q == 0) ? (short)0x3F80 : (short)0;  // bf16(1.0)

    f32x4v acc_init;
#pragma unroll
    for (int r = 0; r < 4; ++r) {
        const int bond = 4 * q + r;
        acc_init[r] = (bond < NBT) ? bbs[bond] : 0.0f;
    }
    const u32x4* a1p = A1pre + lane;
    const u32x4* a2p = A2pre + lane;
    const int qh = q >> 1;
    const int qw = 2 * (q & 1);
    const int mw = m * 4;

    // ============ issue phase: indices for BOTH tiles ============
    const unsigned jA = (unsigned)eidx[ka + m];
    const unsigned iA = (unsigned)eidx[E_EDGES + ka + m];
    const unsigned jB = (unsigned)eidx[kb + m];
    const unsigned iB = (unsigned)eidx[E_EDGES + kb + m];

    const char* siA = (const char*)(sact16 + (size_t)iA * IN_DIM);  // 512 B rows
    const char* sjA = (const char*)(sact16 + (size_t)jA * IN_DIM);
    const char* siB = (const char*)(sact16 + (size_t)iB * IN_DIM);
    const char* sjB = (const char*)(sact16 + (size_t)jB * IN_DIM);

    const unsigned keyFA = (jA << 12) | iA, keyRA = (iA << 12) | jA;
    const unsigned keyFB = (jB << 12) | iB, keyRB = (iB << 12) | jB;
    const unsigned hFA = hashh(keyFA), hRA = hashh(keyRA);
    const unsigned hFB = hashh(keyFB), hRB = hashh(keyRB);

    // 8 speculative 2-slot probes (static) — fly in parallel with staging
    const unsigned long long sFA0 = tab[hFA];
    const unsigned long long sFA1 = tab[(hFA + 1u) & TMASK];
    const unsigned long long sRA0 = tab[hRA];
    const unsigned long long sRA1 = tab[(hRA + 1u) & TMASK];
    const unsigned long long sFB0 = tab[hFB];
    const unsigned long long sFB1 = tab[(hFB + 1u) & TMASK];
    const unsigned long long sRB0 = tab[hRB];
    const unsigned long long sRB1 = tab[(hRB + 1u) & TMASK];

    // staging clusters (SB0-pinned, 4 static ops each)
    auto stage_q = [&](const char* si_b, const char* sj_b, int p, int qb) {
        gld_lds16(si_b + p * 128 + (q)     * 16, (char*)myl + qb);
        gld_lds16(si_b + p * 128 + (4 + q) * 16, (char*)myl + qb + 1024);
        gld_lds16(sj_b + p * 128 + (q)     * 16, (char*)myl + qb + 2048);
        gld_lds16(sj_b + p * 128 + (4 + q) * 16, (char*)myl + qb + 3072);
        SB0();
    };

    stage_q(siA, sjA, 0, 0);        // A.Q0 -> X
    stage_q(siA, sjA, 1, 4096);     // A.Q1 -> Y

    // ---- resolve A (dynamic slow-path loads: older than all later clusters)
    const int wfA = resolve2(tab, keyFA, sFA0, sFA1, hFA);
    const int wrA = resolve2(tab, keyRA, sRA0, sRA1, hRA);
    const float rscA = (wrA >= 0) ? 0.5f : 0.0f;
    const int   wrcA = (wrA >= 0) ? wrA : 0;
    const f32x4 efA = *(const f32x4*)(e + (size_t)wfA  * EDGE_DIM + 4 * q);  // static
    const f32x4 erA = *(const f32x4*)(e + (size_t)wrcA * EDGE_DIM + 4 * q);  // static

    union { bf16x8 v; short s[8]; unsigned u[4]; } B1A;
    {
        const f32x4 es = efA * 0.5f + erA * rscA;
        B1A.u[0] = pack_bf16x2(es[0], es[1]);
        B1A.u[1] = pack_bf16x2(es[2], es[3]);
        B1A.s[4] = one_q0; B1A.s[5] = 0;
        B1A.u[3] = 0u;
    }

    f32x4v acc0 = acc_init;
    f32x4v acc1 = {0.0f, 0.0f, 0.0f, 0.0f};

    // quarter compute: groups g = gbase..gbase+3, buffer at u32 offset qb4
    auto qcompute = [&](int qb4, int gbase, const bf16x8 B1v) {
#pragma unroll
        for (int gp = 0; gp < 4; ++gp) {
            const int g   = gbase + gp;
            const int cl  = 2 * gp + qh;                                  // 0..7
            const int off = (cl >> 2) * 256 + (cl & 3) * 64 + mw + qw;    // u32 units

            const u32x2 wi = *(const u32x2*)(myl + qb4 + off);
            const u32x2 wj = *(const u32x2*)(myl + qb4 + 512 + off);

            f32x4v C1;
            C1[0] = bf_lo(wi.x) + bf_lo(wj.x);
            C1[1] = bf_hi(wi.x) + bf_hi(wj.x);
            C1[2] = bf_lo(wi.y) + bf_lo(wj.y);
            C1[3] = bf_hi(wi.y) + bf_hi(wj.y);

            const u32x4 r1 = a1p[g * 64];
            const u32x4 r2 = a2p[g * 64];
            union { bf16x8 v; unsigned u[4]; } A1, A2;
            A1.u[0] = r1.x; A1.u[1] = r1.y; A1.u[2] = r1.z; A1.u[3] = 0u;
            A2.u[0] = r2.x; A2.u[1] = r2.y; A2.u[2] = 0u;   A2.u[3] = 0u;

            const f32x4v P = __builtin_amdgcn_mfma_f32_16x16x32_bf16(A1.v, B1v, C1, 0, 0, 0);

            union { bf16x8 v; unsigned u[4]; } B2;
            B2.u[0] = pack_bf16x2(silu_f(P[0]), silu_f(P[1]));
            B2.u[1] = pack_bf16x2(silu_f(P[2]), silu_f(P[3]));
            B2.u[2] = 0u; B2.u[3] = 0u;

            if (gp & 1) acc1 = __builtin_amdgcn_mfma_f32_16x16x32_bf16(A2.v, B2.v, acc1, 0, 0, 0);
            else        acc0 = __builtin_amdgcn_mfma_f32_16x16x32_bf16(A2.v, B2.v, acc0, 0, 0, 0);
        }
    };

    auto store_bonds = [&](int k0, const f32x4v accT) {
        float* op = out + BONDS_OFF + (size_t)(k0 + m) * NBT;
        if (q == 0) {
            __builtin_nontemporal_store(accT[0], op + 0);
            __builtin_nontemporal_store(accT[1], op + 1);
            __builtin_nontemporal_store(accT[2], op + 2);
            __builtin_nontemporal_store(accT[3], op + 3);
        } else if (q == 1) {
            __builtin_nontemporal_store(accT[0], op + 4);
        }
    };

    // ============ tile A pipeline ============
    VMW(2);                              // {A.Q0,A.Q1} retired (younger static: efA,erA = 2)
    qcompute(0, 0, B1A.v);               // A.p0 @ X
    LGKM0();
    stage_q(siA, sjA, 2, 0);             // A.Q2 -> X

    qcompute(1024, 4, B1A.v);            // A.p1 @ Y (covered by VMW(2))
    LGKM0();
    stage_q(siA, sjA, 3, 4096);          // A.Q3 -> Y

    VMW(4);                              // A.Q2 retired (younger static: A.Q3 = 4)
    qcompute(0, 8, B1A.v);               // A.p2 @ X
    LGKM0();
    stage_q(siB, sjB, 0, 0);             // B.Q0 -> X

    // ---- resolve B under A's remaining compute (dyn loads: uncounted)
    const int wfB = resolve2(tab, keyFB, sFB0, sFB1, hFB);
    const int wrB = resolve2(tab, keyRB, sRB0, sRB1, hRB);
    const float rscB = (wrB >= 0) ? 0.5f : 0.0f;
    const int   wrcB = (wrB >= 0) ? wrB : 0;
    const f32x4 efB = *(const f32x4*)(e + (size_t)wfB  * EDGE_DIM + 4 * q);  // static
    const f32x4 erB = *(const f32x4*)(e + (size_t)wrcB * EDGE_DIM + 4 * q);  // static

    VMW(6);                              // A.Q3 retired (younger static: B.Q0=4 + efB,erB=2)
    qcompute(1024, 12, B1A.v);           // A.p3 @ Y
    LGKM0();
    stage_q(siB, sjB, 1, 4096);          // B.Q1 -> Y

    store_bonds(ka, acc0 + acc1);        // tile A done (stores never counted)

    union { bf16x8 v; short s[8]; unsigned u[4]; } B1B;
    {
        const f32x4 es = efB * 0.5f + erB * rscB;   // compiler waits efB/erB here
        B1B.u[0] = pack_bf16x2(es[0], es[1]);
        B1B.u[1] = pack_bf16x2(es[2], es[3]);
        B1B.s[4] = one_q0; B1B.s[5] = 0;
        B1B.u[3] = 0u;
    }
    acc0 = acc_init;
    acc1 = (f32x4v){0.0f, 0.0f, 0.0f, 0.0f};

    // ============ tile B pipeline ============
    VMW(4);                              // B.Q0 retired (younger static loads: B.Q1 = 4;
                                         //  true younger count >= 6 -> stricter, safe)
    qcompute(0, 0, B1B.v);               // B.p0 @ X
    LGKM0();
    stage_q(siB, sjB, 2, 0);             // B.Q2 -> X

    VMW(4);                              // B.Q1 retired (younger static: B.Q2 = 4)
    qcompute(1024, 4, B1B.v);            // B.p1 @ Y
    LGKM0();
    stage_q(siB, sjB, 3, 4096);          // B.Q3 -> Y

    VMW(4);                              // B.Q2 retired (younger static: B.Q3 = 4)
    qcompute(0, 8, B1B.v);               // B.p2 @ X

    VMW(0);                              // B.Q3 retired
    qcompute(1024, 12, B1B.v);           // B.p3 @ Y

    store_bonds(kb, acc0 + acc1);
}

// ---------------------------------------------------------------------------
extern "C" void kernel_launch(void* const* d_in, const int* in_sizes, int n_in,
                              void* d_out, int out_size, void* d_ws, size_t ws_size,
                              hipStream_t stream) {
    const float* s   = (const float*)d_in[0];
    const float* e   = (const float*)d_in[1];
    const int*   eix = (const int*)d_in[3];
    const float* Wsh = (const float*)d_in[4];
    const float* bsh = (const float*)d_in[5];
    const float* Wb  = (const float*)d_in[6];
    const float* bbo = (const float*)d_in[7];
    const float* Wbs = (const float*)d_in[8];
    const float* bbs = (const float*)d_in[9];
    const float* Wa  = (const float*)d_in[10];
    const float* ba  = (const float*)d_in[11];
    float* out = (float*)d_out;

    char* ws = (char*)d_ws;
    unsigned short*     sact16 = (unsigned short*)ws;             // 2 MB @ 0
    u32x4*              A1pre  = (u32x4*)(ws + (2u << 20));       // 16 KB
    u32x4*              A2pre  = (u32x4*)(ws + (2u << 20) + 16384);
    unsigned long long* tab    = (unsigned long long*)(ws + (3u << 20)); // 8 MB

    (void)hipMemsetAsync(tab, 0x00, TSIZE * sizeof(unsigned long long), stream);

    k_front<<<2049, 256, 0, stream>>>(s, Wsh, bsh, eix, Wb, bbo, Wbs,
                                      sact16, tab, A1pre, A2pre);
    k_edges_mfma<<<2624, 256, 0, stream>>>(eix, e, tab, sact16,
                                           A1pre, A2pre, bbs, Wa, ba, out);
}

// Round 7
// 192.080 us; speedup vs baseline: 1.1369x; 1.1369x over previous
//
#include <hip/hip_runtime.h>
#include <hip/hip_bf16.h>

#define N_NODES   4096
#define E_EDGES   262144
#define IN_DIM    256
#define EDGE_DIM  16
#define NAF       16
#define LATENT    128
#define NBT       5

#define LATENT_OFF 0
#define ATOMS_OFF  (N_NODES * LATENT)                 // 524288
#define BONDS_OFF  (ATOMS_OFF + N_NODES * NAF)        // 589824

// hash table: 2^20 u64 slots = 8 MB, load factor 0.25
#define TBITS 20
#define TSIZE (1u << TBITS)
#define TMASK (TSIZE - 1u)

typedef float    f32x4  __attribute__((ext_vector_type(4)));
typedef float    f32x4v __attribute__((ext_vector_type(4)));
typedef short    bf16x8 __attribute__((ext_vector_type(8)));
typedef unsigned u32x2  __attribute__((ext_vector_type(2)));
typedef unsigned u32x4  __attribute__((ext_vector_type(4)));

// silu via v_rcp_f32 (accuracy validated in R1: absmax unchanged)
__device__ __forceinline__ float silu_f(float x) {
    return x * __builtin_amdgcn_rcpf(1.0f + __expf(-x));
}

__device__ __forceinline__ unsigned pack_bf16x2(float lo, float hi) {
#if __has_builtin(__builtin_amdgcn_cvt_pk_bf16_f32)
    typedef __bf16 bf16x2_t __attribute__((ext_vector_type(2)));
    union { bf16x2_t v; unsigned u; } c;
    c.v = __builtin_amdgcn_cvt_pk_bf16_f32(lo, hi);
    return c.u;
#else
    union { float f; unsigned u; } a, b;
    a.f = lo; b.f = hi;
    const unsigned ra = (a.u + 0x7FFFu + ((a.u >> 16) & 1u)) >> 16;
    const unsigned rb = (b.u + 0x7FFFu + ((b.u >> 16) & 1u)) >> 16;
    return ra | (rb << 16);
#endif
}

__device__ __forceinline__ float bf_lo(unsigned u) {
    union { unsigned x; float f; } c; c.x = u << 16; return c.f;
}
__device__ __forceinline__ float bf_hi(unsigned u) {
    union { unsigned x; float f; } c; c.x = u & 0xFFFF0000u; return c.f;
}

// split fp32x8 into bf16 hi + bf16 lo fragments (x = hi + lo exactly to 2^-18)
__device__ __forceinline__ void split_bf16(const float4 x0, const float4 x1,
                                           bf16x8* hi, bf16x8* lo) {
    union { bf16x8 v; unsigned u[4]; } H, L;
    H.u[0] = pack_bf16x2(x0.x, x0.y);
    H.u[1] = pack_bf16x2(x0.z, x0.w);
    H.u[2] = pack_bf16x2(x1.x, x1.y);
    H.u[3] = pack_bf16x2(x1.z, x1.w);
    L.u[0] = pack_bf16x2(x0.x - bf_lo(H.u[0]), x0.y - bf_hi(H.u[0]));
    L.u[1] = pack_bf16x2(x0.z - bf_lo(H.u[1]), x0.w - bf_hi(H.u[1]));
    L.u[2] = pack_bf16x2(x1.x - bf_lo(H.u[2]), x1.y - bf_hi(H.u[2]));
    L.u[3] = pack_bf16x2(x1.z - bf_lo(H.u[3]), x1.w - bf_hi(H.u[3]));
    *hi = H.v; *lo = L.v;
}

// async gather: per-lane 16B global -> LDS[uniform base + lane*16]
__device__ __forceinline__ void gld_lds16(const void* g, void* l) {
    __builtin_amdgcn_global_load_lds(
        (const __attribute__((address_space(1))) unsigned*)g,
        (__attribute__((address_space(3))) unsigned*)l, 16, 0, 0);
}

__device__ __forceinline__ unsigned hashh(unsigned key) {
    return (key * 2654435761u) >> (32 - TBITS);
}

// 2-slot speculative resolve (R5, validated).
__device__ __forceinline__ int resolve2(const unsigned long long* __restrict__ tab,
                                        unsigned key, unsigned long long s0,
                                        unsigned long long s1, unsigned h) {
    if ((unsigned)(s0 >> 18) == key + 1u) return (int)(s0 & 0x3FFFFu);
    if (s0 == 0ULL) return -1;
    if ((unsigned)(s1 >> 18) == key + 1u) return (int)(s1 & 0x3FFFFu);
    if (s1 == 0ULL) return -1;
    h = (h + 2u) & TMASK;
    while (true) {
        const unsigned long long cur = tab[h];
        if (cur == 0ULL) return -1;
        if ((unsigned)(cur >> 18) == key + 1u) return (int)(cur & 0x3FFFFu);
        h = (h + 1u) & TMASK;
    }
}

// 1-slot speculative resolve (lower register pressure for tile B).
__device__ __forceinline__ int resolve1(const unsigned long long* __restrict__ tab,
                                        unsigned key, unsigned long long s0,
                                        unsigned h) {
    if ((unsigned)(s0 >> 18) == key + 1u) return (int)(s0 & 0x3FFFFu);
    if (s0 == 0ULL) return -1;
    h = (h + 1u) & TMASK;
    while (true) {
        const unsigned long long cur = tab[h];
        if (cur == 0ULL) return -1;
        if ((unsigned)(cur >> 18) == key + 1u) return (int)(cur & 0x3FFFFu);
        h = (h + 1u) & TMASK;
    }
}

// ---------------------------------------------------------------------------
// k_front: blocks 0..1023  : GEMM1
//          blocks 1024..2047: hash insert (direct-CAS)
//          block  2048      : prepack A1pre/A2pre
// ---------------------------------------------------------------------------
__global__ __launch_bounds__(256) void k_front(const float* __restrict__ s,
                                               const float* __restrict__ Wsh,
                                               const float* __restrict__ bsh,
                                               const int* __restrict__ eidx,
                                               const float* __restrict__ Wb,
                                               const float* __restrict__ bb,
                                               const float* __restrict__ Wbs,
                                               unsigned short* __restrict__ sact16,
                                               unsigned long long* __restrict__ tab,
                                               u32x4* __restrict__ A1pre,
                                               u32x4* __restrict__ A2pre) {
    const int blk = blockIdx.x;
    const int c   = threadIdx.x;

    if (blk >= 1024) {
        if (blk < 2048) {
            // ---- hash insert (winner = max edge id per key), direct CAS
            const int k = (blk - 1024) * 256 + c;
            const unsigned j = (unsigned)eidx[k];
            const unsigned i = (unsigned)eidx[E_EDGES + k];
            const unsigned key = (j << 12) | i;
            const unsigned long long mine =
                ((unsigned long long)(key + 1u) << 18) | (unsigned)k;
            unsigned h = hashh(key);
            while (true) {
                const unsigned long long old = atomicCAS(&tab[h], 0ULL, mine);
                if (old == 0ULL) return;                    // claimed empty slot
                if ((unsigned)(old >> 18) == key + 1u) {    // key already present
                    atomicMax(&tab[h], mine);
                    return;
                }
                h = (h + 1u) & TMASK;
            }
        } else {
            // ---- prepack: A1 = {Wb pair x2, pk(bb,0), 0}; A2 = {Wbs pair x2, 0, 0}
#pragma unroll
            for (int ee = 0; ee < 4; ++ee) {
                const int idx  = c + 256 * ee;
                const int g    = idx >> 6;
                const int lane = idx & 63;
                const int mm   = lane & 15;
                const int qq   = lane >> 4;

                const float4 w = *(const float4*)(Wb + (16 * g + mm) * EDGE_DIM + 4 * qq);
                u32x4 r1;
                r1.x = pack_bf16x2(w.x, w.y);
                r1.y = pack_bf16x2(w.z, w.w);
                r1.z = pack_bf16x2(bb[16 * g + mm], 0.0f);
                r1.w = 0u;
                A1pre[idx] = r1;

                u32x4 r2;
                if (mm < NBT) {
                    const float4 ws = *(const float4*)(Wbs + mm * IN_DIM + 16 * g + 4 * qq);
                    r2.x = pack_bf16x2(ws.x, ws.y);
                    r2.y = pack_bf16x2(ws.z, ws.w);
                } else {
                    r2.x = 0u; r2.y = 0u;
                }
                r2.z = 0u; r2.w = 0u;
                A2pre[idx] = r2;
            }
        }
        return;
    }

    // ---- GEMM1 tile: wave -> (row_tile, col_tile); 256 x 16 tiles
    const int lane = c & 63;
    const int wv   = c >> 6;
    const int wave = blk * 4 + wv;
    const int m    = lane & 15;
    const int q    = lane >> 4;
    const int row0 = (wave >> 4) * 16;
    const int col0 = (wave & 15) * 16;

    f32x4v acc;
    {
        const float bias = bsh[col0 + m];
        acc[0] = bias; acc[1] = bias; acc[2] = bias; acc[3] = bias;
    }

    const float* ap = s   + (size_t)(row0 + m) * IN_DIM + 8 * q;
    const float* bp = Wsh + (size_t)(col0 + m) * IN_DIM + 8 * q;

#pragma unroll
    for (int c8 = 0; c8 < 8; ++c8) {
        const float4 a0 = *(const float4*)(ap + 32 * c8);
        const float4 a1 = *(const float4*)(ap + 32 * c8 + 4);
        const float4 b0 = *(const float4*)(bp + 32 * c8);
        const float4 b1 = *(const float4*)(bp + 32 * c8 + 4);
        bf16x8 Ah, Al, Bh, Bl;
        split_bf16(a0, a1, &Ah, &Al);
        split_bf16(b0, b1, &Bh, &Bl);
        acc = __builtin_amdgcn_mfma_f32_16x16x32_bf16(Ah, Bh, acc, 0, 0, 0);
        acc = __builtin_amdgcn_mfma_f32_16x16x32_bf16(Al, Bh, acc, 0, 0, 0);
        acc = __builtin_amdgcn_mfma_f32_16x16x32_bf16(Ah, Bl, acc, 0, 0, 0);
    }

#pragma unroll
    for (int r = 0; r < 4; ++r) {
        const int row = row0 + 4 * q + r;
        const float v = silu_f(acc[r]);
        sact16[(size_t)row * IN_DIM + col0 + m] =
            (unsigned short)(pack_bf16x2(v, 0.0f) & 0xFFFFu);
    }
}

// fence helpers. Counted-wait safety rule (R3 post-mortem, R4/R5 validated):
// vmcnt(N) targeting cluster X requires N <= #STATICALLY-issued loads younger
// than X not yet provably retired. Dynamic loads (hash slow path) are legal
// anywhere but NEVER counted -> FIFO retirement only makes waits stricter.
// qcompute's A1pre/A2pre loads are consumed (compiler-waited) in-phase ->
// retired before the next hand wait -> never loosen a count.
#define SB0()    __builtin_amdgcn_sched_barrier(0)
#define LGKM0()  do { __asm__ __volatile__("s_waitcnt lgkmcnt(0)" ::: "memory"); SB0(); } while (0)
#define VMW(n)   do { __asm__ __volatile__("s_waitcnt vmcnt(" #n ")" ::: "memory"); SB0(); } while (0)

// ---------------------------------------------------------------------------
// k_edges_mfma: blocks 0..2047  : edge tiles, 2 tiles/wave (A,B); tile B's
//                                 front chain (probes, resolve, e) hides under
//                                 tile A's compute. R7: launch_bounds(256,4)
//                                 (128 VGPR -> no spill; R6 spilled at 5) and
//                                 1-slot B probes to trim live state.
//               blocks 2048..2623: GEMM2 — atoms/latent = sact16@Wa^T + ba
// LDS: 8 KB/wave = 2 x 4 KB quarter-buffers -> 32 KB/block.
// ---------------------------------------------------------------------------
__global__ __launch_bounds__(256, 4) void k_edges_mfma(const int* __restrict__ eidx,
                                                       const float* __restrict__ e,
                                                       const unsigned long long* __restrict__ tab,
                                                       const unsigned short* __restrict__ sact16,
                                                       const u32x4* __restrict__ A1pre,
                                                       const u32x4* __restrict__ A2pre,
                                                       const float* __restrict__ bbs,
                                                       const float* __restrict__ Wa,
                                                       const float* __restrict__ ba,
                                                       float* __restrict__ out) {
    __shared__ unsigned lds_all[4][2048];   // 8 KB/wave
    const int blk  = blockIdx.x;
    const int lane = threadIdx.x & 63;
    const int wv   = threadIdx.x >> 6;
    const int m    = lane & 15;
    const int q    = lane >> 4;

    if (blk >= 2048) {
        // ---- GEMM2: wave -> (row_tile, col_tile) over 256 x 9 tiles
        const int wave = (blk - 2048) * 4 + wv;   // 0..2303
        const int rt = wave / 9;
        const int ct = wave - rt * 9;
        const int row0  = rt * 16;
        const int n_abs = ct * 16 + m;            // 0..143

        f32x4v acc;
        {
            const float bias = ba[n_abs];
            acc[0] = bias; acc[1] = bias; acc[2] = bias; acc[3] = bias;
        }

        const unsigned short* apu = sact16 + (size_t)(row0 + m) * IN_DIM + 8 * q;
        const float*          bp  = Wa + (size_t)n_abs * IN_DIM + 8 * q;

#pragma unroll
        for (int c8 = 0; c8 < 8; ++c8) {
            const bf16x8 A = *(const bf16x8*)(apu + 32 * c8);
            const float4 b0 = *(const float4*)(bp + 32 * c8);
            const float4 b1 = *(const float4*)(bp + 32 * c8 + 4);
            bf16x8 Bh, Bl;
            split_bf16(b0, b1, &Bh, &Bl);
            acc = __builtin_amdgcn_mfma_f32_16x16x32_bf16(A, Bh, acc, 0, 0, 0);
            acc = __builtin_amdgcn_mfma_f32_16x16x32_bf16(A, Bl, acc, 0, 0, 0);
        }
#pragma unroll
        for (int r = 0; r < 4; ++r) {
            const int row = row0 + 4 * q + r;
            if (n_abs < NAF)
                out[ATOMS_OFF + (size_t)row * NAF + n_abs] = acc[r];
            else
                out[LATENT_OFF + (size_t)row * LATENT + (n_abs - NAF)] = acc[r];
        }
        return;
    }

    // ---- edge path: this wave owns tiles ka = wave*32, kb = ka+16
    const int wave = blk * 4 + wv;
    const int ka   = __builtin_amdgcn_readfirstlane(wave * 32);
    const int kb   = ka + 16;
    unsigned* myl  = lds_all[wv];
    const short one_q0 = (q == 0) ? (short)0x3F80 : (short)0;  // bf16(1.0)

    f32x4v acc_init;
#pragma unroll
    for (int r = 0; r < 4; ++r) {
        const int bond = 4 * q + r;
        acc_init[r] = (bond < NBT) ? bbs[bond] : 0.0f;
    }
    const u32x4* a1p = A1pre + lane;
    const u32x4* a2p = A2pre + lane;
    const int qh = q >> 1;
    const int qw = 2 * (q & 1);
    const int mw = m * 4;

    // ============ issue phase ============
    const unsigned jA = (unsigned)eidx[ka + m];
    const unsigned iA = (unsigned)eidx[E_EDGES + ka + m];
    const unsigned jB = (unsigned)eidx[kb + m];
    const unsigned iB = (unsigned)eidx[E_EDGES + kb + m];

    const char* siA = (const char*)(sact16 + (size_t)iA * IN_DIM);  // 512 B rows
    const char* sjA = (const char*)(sact16 + (size_t)jA * IN_DIM);

    const unsigned keyFA = (jA << 12) | iA, keyRA = (iA << 12) | jA;
    const unsigned keyFB = (jB << 12) | iB, keyRB = (iB << 12) | jB;
    const unsigned hFA = hashh(keyFA), hRA = hashh(keyRA);
    const unsigned hFB = hashh(keyFB), hRB = hashh(keyRB);

    // A: 2-slot speculative probes; B: 1-slot (trimmed live state)
    const unsigned long long sFA0 = tab[hFA];
    const unsigned long long sFA1 = tab[(hFA + 1u) & TMASK];
    const unsigned long long sRA0 = tab[hRA];
    const unsigned long long sRA1 = tab[(hRA + 1u) & TMASK];
    const unsigned long long sFB0 = tab[hFB];
    const unsigned long long sRB0 = tab[hRB];

    // staging clusters (SB0-pinned, 4 static ops each)
    auto stage_q = [&](const char* si_b, const char* sj_b, int p, int qb) {
        gld_lds16(si_b + p * 128 + (q)     * 16, (char*)myl + qb);
        gld_lds16(si_b + p * 128 + (4 + q) * 16, (char*)myl + qb + 1024);
        gld_lds16(sj_b + p * 128 + (q)     * 16, (char*)myl + qb + 2048);
        gld_lds16(sj_b + p * 128 + (4 + q) * 16, (char*)myl + qb + 3072);
        SB0();
    };

    stage_q(siA, sjA, 0, 0);        // A.Q0 -> X
    stage_q(siA, sjA, 1, 4096);     // A.Q1 -> Y

    // ---- resolve A (dynamic slow-path loads: uncounted, only stricter)
    const int wfA = resolve2(tab, keyFA, sFA0, sFA1, hFA);
    const int wrA = resolve2(tab, keyRA, sRA0, sRA1, hRA);
    const float rscA = (wrA >= 0) ? 0.5f : 0.0f;
    const int   wrcA = (wrA >= 0) ? wrA : 0;
    const f32x4 efA = *(const f32x4*)(e + (size_t)wfA  * EDGE_DIM + 4 * q);  // static
    const f32x4 erA = *(const f32x4*)(e + (size_t)wrcA * EDGE_DIM + 4 * q);  // static

    union { bf16x8 v; short s[8]; unsigned u[4]; } B1A;
    {
        const f32x4 es = efA * 0.5f + erA * rscA;
        B1A.u[0] = pack_bf16x2(es[0], es[1]);
        B1A.u[1] = pack_bf16x2(es[2], es[3]);
        B1A.s[4] = one_q0; B1A.s[5] = 0;
        B1A.u[3] = 0u;
    }

    f32x4v acc0 = acc_init;
    f32x4v acc1 = {0.0f, 0.0f, 0.0f, 0.0f};

    // quarter compute: groups g = gbase..gbase+3, buffer at u32 offset qb4
    auto qcompute = [&](int qb4, int gbase, const bf16x8 B1v) {
#pragma unroll
        for (int gp = 0; gp < 4; ++gp) {
            const int g   = gbase + gp;
            const int cl  = 2 * gp + qh;                                  // 0..7
            const int off = (cl >> 2) * 256 + (cl & 3) * 64 + mw + qw;    // u32 units

            const u32x2 wi = *(const u32x2*)(myl + qb4 + off);
            const u32x2 wj = *(const u32x2*)(myl + qb4 + 512 + off);

            f32x4v C1;
            C1[0] = bf_lo(wi.x) + bf_lo(wj.x);
            C1[1] = bf_hi(wi.x) + bf_hi(wj.x);
            C1[2] = bf_lo(wi.y) + bf_lo(wj.y);
            C1[3] = bf_hi(wi.y) + bf_hi(wj.y);

            const u32x4 r1 = a1p[g * 64];
            const u32x4 r2 = a2p[g * 64];
            union { bf16x8 v; unsigned u[4]; } A1, A2;
            A1.u[0] = r1.x; A1.u[1] = r1.y; A1.u[2] = r1.z; A1.u[3] = 0u;
            A2.u[0] = r2.x; A2.u[1] = r2.y; A2.u[2] = 0u;   A2.u[3] = 0u;

            const f32x4v P = __builtin_amdgcn_mfma_f32_16x16x32_bf16(A1.v, B1v, C1, 0, 0, 0);

            union { bf16x8 v; unsigned u[4]; } B2;
            B2.u[0] = pack_bf16x2(silu_f(P[0]), silu_f(P[1]));
            B2.u[1] = pack_bf16x2(silu_f(P[2]), silu_f(P[3]));
            B2.u[2] = 0u; B2.u[3] = 0u;

            if (gp & 1) acc1 = __builtin_amdgcn_mfma_f32_16x16x32_bf16(A2.v, B2.v, acc1, 0, 0, 0);
            else        acc0 = __builtin_amdgcn_mfma_f32_16x16x32_bf16(A2.v, B2.v, acc0, 0, 0, 0);
        }
    };

    auto store_bonds = [&](int k0, const f32x4v accT) {
        float* op = out + BONDS_OFF + (size_t)(k0 + m) * NBT;
        if (q == 0) {
            __builtin_nontemporal_store(accT[0], op + 0);
            __builtin_nontemporal_store(accT[1], op + 1);
            __builtin_nontemporal_store(accT[2], op + 2);
            __builtin_nontemporal_store(accT[3], op + 3);
        } else if (q == 1) {
            __builtin_nontemporal_store(accT[0], op + 4);
        }
    };

    // ============ tile A pipeline ============
    VMW(2);                              // {A.Q0,A.Q1} retired (younger static: efA,erA)
    qcompute(0, 0, B1A.v);               // A.p0 @ X
    LGKM0();
    stage_q(siA, sjA, 2, 0);             // A.Q2 -> X

    qcompute(1024, 4, B1A.v);            // A.p1 @ Y (covered by VMW(2))
    LGKM0();
    stage_q(siA, sjA, 3, 4096);          // A.Q3 -> Y

    VMW(4);                              // A.Q2 retired (younger static: A.Q3 = 4)
    qcompute(0, 8, B1A.v);               // A.p2 @ X
    LGKM0();
    const char* siB = (const char*)(sact16 + (size_t)iB * IN_DIM);
    const char* sjB = (const char*)(sact16 + (size_t)jB * IN_DIM);
    stage_q(siB, sjB, 0, 0);             // B.Q0 -> X

    // ---- resolve B under A's remaining compute (dyn loads: uncounted)
    const int wfB = resolve1(tab, keyFB, sFB0, hFB);
    const int wrB = resolve1(tab, keyRB, sRB0, hRB);
    const float rscB = (wrB >= 0) ? 0.5f : 0.0f;
    const int   wrcB = (wrB >= 0) ? wrB : 0;
    const f32x4 efB = *(const f32x4*)(e + (size_t)wfB  * EDGE_DIM + 4 * q);  // static
    const f32x4 erB = *(const f32x4*)(e + (size_t)wrcB * EDGE_DIM + 4 * q);  // static

    VMW(6);                              // A.Q3 retired (younger static: B.Q0=4 + efB,erB)
    qcompute(1024, 12, B1A.v);           // A.p3 @ Y
    LGKM0();
    stage_q(siB, sjB, 1, 4096);          // B.Q1 -> Y

    store_bonds(ka, acc0 + acc1);        // tile A done (stores never counted)

    union { bf16x8 v; short s[8]; unsigned u[4]; } B1B;
    {
        const f32x4 es = efB * 0.5f + erB * rscB;   // compiler wait here also
        B1B.u[0] = pack_bf16x2(es[0], es[1]);       // retires B.Q0 (older, FIFO)
        B1B.u[1] = pack_bf16x2(es[2], es[3]);
        B1B.s[4] = one_q0; B1B.s[5] = 0;
        B1B.u[3] = 0u;
    }
    acc0 = acc_init;
    acc1 = (f32x4v){0.0f, 0.0f, 0.0f, 0.0f};

    // ============ tile B pipeline ============
    VMW(4);                              // B.Q0 retired (younger static: B.Q1 = 4;
                                         //  usually trivially satisfied via B1B wait)
    qcompute(0, 0, B1B.v);               // B.p0 @ X
    LGKM0();
    stage_q(siB, sjB, 2, 0);             // B.Q2 -> X

    VMW(4);                              // B.Q1 retired (younger static: B.Q2 = 4)
    qcompute(1024, 4, B1B.v);            // B.p1 @ Y
    LGKM0();
    stage_q(siB, sjB, 3, 4096);          // B.Q3 -> Y

    VMW(4);                              // B.Q2 retired (younger static: B.Q3 = 4)
    qcompute(0, 8, B1B.v);               // B.p2 @ X

    VMW(0);                              // B.Q3 retired
    qcompute(1024, 12, B1B.v);           // B.p3 @ Y

    store_bonds(kb, acc0 + acc1);
}

// ---------------------------------------------------------------------------
extern "C" void kernel_launch(void* const* d_in, const int* in_sizes, int n_in,
                              void* d_out, int out_size, void* d_ws, size_t ws_size,
                              hipStream_t stream) {
    const float* s   = (const float*)d_in[0];
    const float* e   = (const float*)d_in[1];
    const int*   eix = (const int*)d_in[3];
    const float* Wsh = (const float*)d_in[4];
    const float* bsh = (const float*)d_in[5];
    const float* Wb  = (const float*)d_in[6];
    const float* bbo = (const float*)d_in[7];
    const float* Wbs = (const float*)d_in[8];
    const float* bbs = (const float*)d_in[9];
    const float* Wa  = (const float*)d_in[10];
    const float* ba  = (const float*)d_in[11];
    float* out = (float*)d_out;

    char* ws = (char*)d_ws;
    unsigned short*     sact16 = (unsigned short*)ws;             // 2 MB @ 0
    u32x4*              A1pre  = (u32x4*)(ws + (2u << 20));       // 16 KB
    u32x4*              A2pre  = (u32x4*)(ws + (2u << 20) + 16384);
    unsigned long long* tab    = (unsigned long long*)(ws + (3u << 20)); // 8 MB

    (void)hipMemsetAsync(tab, 0x00, TSIZE * sizeof(unsigned long long), stream);

    k_front<<<2049, 256, 0, stream>>>(s, Wsh, bsh, eix, Wb, bbo, Wbs,
                                      sact16, tab, A1pre, A2pre);
    k_edges_mfma<<<2624, 256, 0, stream>>>(eix, e, tab, sact16,
                                           A1pre, A2pre, bbs, Wa, ba, out);
}

// Round 8
// 175.130 us; speedup vs baseline: 1.2469x; 1.0968x over previous
//
#include <hip/hip_runtime.h>
#include <hip/hip_bf16.h>

#define N_NODES   4096
#define E_EDGES   262144
#define IN_DIM    256
#define EDGE_DIM  16
#define NAF       16
#define LATENT    128
#define NBT       5

#define LATENT_OFF 0
#define ATOMS_OFF  (N_NODES * LATENT)                 // 524288
#define BONDS_OFF  (ATOMS_OFF + N_NODES * NAF)        // 589824

// hash table: 2^20 u64 slots = 8 MB, load factor 0.25
#define TBITS 20
#define TSIZE (1u << TBITS)
#define TMASK (TSIZE - 1u)

typedef float    f32x4  __attribute__((ext_vector_type(4)));
typedef float    f32x4v __attribute__((ext_vector_type(4)));
typedef short    bf16x8 __attribute__((ext_vector_type(8)));
typedef unsigned u32x2  __attribute__((ext_vector_type(2)));
typedef unsigned u32x4  __attribute__((ext_vector_type(4)));

// silu via v_rcp_f32 (accuracy validated in R1: absmax unchanged)
__device__ __forceinline__ float silu_f(float x) {
    return x * __builtin_amdgcn_rcpf(1.0f + __expf(-x));
}

__device__ __forceinline__ unsigned pack_bf16x2(float lo, float hi) {
#if __has_builtin(__builtin_amdgcn_cvt_pk_bf16_f32)
    typedef __bf16 bf16x2_t __attribute__((ext_vector_type(2)));
    union { bf16x2_t v; unsigned u; } c;
    c.v = __builtin_amdgcn_cvt_pk_bf16_f32(lo, hi);
    return c.u;
#else
    union { float f; unsigned u; } a, b;
    a.f = lo; b.f = hi;
    const unsigned ra = (a.u + 0x7FFFu + ((a.u >> 16) & 1u)) >> 16;
    const unsigned rb = (b.u + 0x7FFFu + ((b.u >> 16) & 1u)) >> 16;
    return ra | (rb << 16);
#endif
}

__device__ __forceinline__ float bf_lo(unsigned u) {
    union { unsigned x; float f; } c; c.x = u << 16; return c.f;
}
__device__ __forceinline__ float bf_hi(unsigned u) {
    union { unsigned x; float f; } c; c.x = u & 0xFFFF0000u; return c.f;
}

// split fp32x8 into bf16 hi + bf16 lo fragments (x = hi + lo exactly to 2^-18)
__device__ __forceinline__ void split_bf16(const float4 x0, const float4 x1,
                                           bf16x8* hi, bf16x8* lo) {
    union { bf16x8 v; unsigned u[4]; } H, L;
    H.u[0] = pack_bf16x2(x0.x, x0.y);
    H.u[1] = pack_bf16x2(x0.z, x0.w);
    H.u[2] = pack_bf16x2(x1.x, x1.y);
    H.u[3] = pack_bf16x2(x1.z, x1.w);
    L.u[0] = pack_bf16x2(x0.x - bf_lo(H.u[0]), x0.y - bf_hi(H.u[0]));
    L.u[1] = pack_bf16x2(x0.z - bf_lo(H.u[1]), x0.w - bf_hi(H.u[1]));
    L.u[2] = pack_bf16x2(x1.x - bf_lo(H.u[2]), x1.y - bf_hi(H.u[2]));
    L.u[3] = pack_bf16x2(x1.z - bf_lo(H.u[3]), x1.w - bf_hi(H.u[3]));
    *hi = H.v; *lo = L.v;
}

// async gather: per-lane 16B global -> LDS[uniform base + lane*16]
__device__ __forceinline__ void gld_lds16(const void* g, void* l) {
    __builtin_amdgcn_global_load_lds(
        (const __attribute__((address_space(1))) unsigned*)g,
        (__attribute__((address_space(3))) unsigned*)l, 16, 0, 0);
}

__device__ __forceinline__ unsigned hashh(unsigned key) {
    return (key * 2654435761u) >> (32 - TBITS);
}

// 2-slot speculative resolve (R5, validated). Slow-path loads are dynamic but
// never counted in any vmcnt N -> only ever make counted waits stricter.
__device__ __forceinline__ int resolve2(const unsigned long long* __restrict__ tab,
                                        unsigned key, unsigned long long s0,
                                        unsigned long long s1, unsigned h) {
    if ((unsigned)(s0 >> 18) == key + 1u) return (int)(s0 & 0x3FFFFu);
    if (s0 == 0ULL) return -1;
    if ((unsigned)(s1 >> 18) == key + 1u) return (int)(s1 & 0x3FFFFu);
    if (s1 == 0ULL) return -1;
    h = (h + 2u) & TMASK;
    while (true) {
        const unsigned long long cur = tab[h];
        if (cur == 0ULL) return -1;
        if ((unsigned)(cur >> 18) == key + 1u) return (int)(cur & 0x3FFFFu);
        h = (h + 1u) & TMASK;
    }
}

// ---------------------------------------------------------------------------
// k_front: blocks 0..1023  : GEMM1
//          blocks 1024..2047: hash insert (direct-CAS, validated R6/R7)
//          block  2048      : prepack A1pre/A2pre
// ---------------------------------------------------------------------------
__global__ __launch_bounds__(256) void k_front(const float* __restrict__ s,
                                               const float* __restrict__ Wsh,
                                               const float* __restrict__ bsh,
                                               const int* __restrict__ eidx,
                                               const float* __restrict__ Wb,
                                               const float* __restrict__ bb,
                                               const float* __restrict__ Wbs,
                                               unsigned short* __restrict__ sact16,
                                               unsigned long long* __restrict__ tab,
                                               u32x4* __restrict__ A1pre,
                                               u32x4* __restrict__ A2pre) {
    const int blk = blockIdx.x;
    const int c   = threadIdx.x;

    if (blk >= 1024) {
        if (blk < 2048) {
            // ---- hash insert (winner = max edge id per key), direct CAS
            const int k = (blk - 1024) * 256 + c;
            const unsigned j = (unsigned)eidx[k];
            const unsigned i = (unsigned)eidx[E_EDGES + k];
            const unsigned key = (j << 12) | i;
            const unsigned long long mine =
                ((unsigned long long)(key + 1u) << 18) | (unsigned)k;
            unsigned h = hashh(key);
            while (true) {
                const unsigned long long old = atomicCAS(&tab[h], 0ULL, mine);
                if (old == 0ULL) return;                    // claimed empty slot
                if ((unsigned)(old >> 18) == key + 1u) {    // key already present
                    atomicMax(&tab[h], mine);
                    return;
                }
                h = (h + 1u) & TMASK;
            }
        } else {
            // ---- prepack: A1 = {Wb pair x2, pk(bb,0), 0}; A2 = {Wbs pair x2, 0, 0}
#pragma unroll
            for (int ee = 0; ee < 4; ++ee) {
                const int idx  = c + 256 * ee;
                const int g    = idx >> 6;
                const int lane = idx & 63;
                const int mm   = lane & 15;
                const int qq   = lane >> 4;

                const float4 w = *(const float4*)(Wb + (16 * g + mm) * EDGE_DIM + 4 * qq);
                u32x4 r1;
                r1.x = pack_bf16x2(w.x, w.y);
                r1.y = pack_bf16x2(w.z, w.w);
                r1.z = pack_bf16x2(bb[16 * g + mm], 0.0f);
                r1.w = 0u;
                A1pre[idx] = r1;

                u32x4 r2;
                if (mm < NBT) {
                    const float4 ws = *(const float4*)(Wbs + mm * IN_DIM + 16 * g + 4 * qq);
                    r2.x = pack_bf16x2(ws.x, ws.y);
                    r2.y = pack_bf16x2(ws.z, ws.w);
                } else {
                    r2.x = 0u; r2.y = 0u;
                }
                r2.z = 0u; r2.w = 0u;
                A2pre[idx] = r2;
            }
        }
        return;
    }

    // ---- GEMM1 tile: wave -> (row_tile, col_tile); 256 x 16 tiles
    const int lane = c & 63;
    const int wv   = c >> 6;
    const int wave = blk * 4 + wv;
    const int m    = lane & 15;
    const int q    = lane >> 4;
    const int row0 = (wave >> 4) * 16;
    const int col0 = (wave & 15) * 16;

    f32x4v acc;
    {
        const float bias = bsh[col0 + m];
        acc[0] = bias; acc[1] = bias; acc[2] = bias; acc[3] = bias;
    }

    const float* ap = s   + (size_t)(row0 + m) * IN_DIM + 8 * q;
    const float* bp = Wsh + (size_t)(col0 + m) * IN_DIM + 8 * q;

#pragma unroll
    for (int c8 = 0; c8 < 8; ++c8) {
        const float4 a0 = *(const float4*)(ap + 32 * c8);
        const float4 a1 = *(const float4*)(ap + 32 * c8 + 4);
        const float4 b0 = *(const float4*)(bp + 32 * c8);
        const float4 b1 = *(const float4*)(bp + 32 * c8 + 4);
        bf16x8 Ah, Al, Bh, Bl;
        split_bf16(a0, a1, &Ah, &Al);
        split_bf16(b0, b1, &Bh, &Bl);
        acc = __builtin_amdgcn_mfma_f32_16x16x32_bf16(Ah, Bh, acc, 0, 0, 0);
        acc = __builtin_amdgcn_mfma_f32_16x16x32_bf16(Al, Bh, acc, 0, 0, 0);
        acc = __builtin_amdgcn_mfma_f32_16x16x32_bf16(Ah, Bl, acc, 0, 0, 0);
    }

#pragma unroll
    for (int r = 0; r < 4; ++r) {
        const int row = row0 + 4 * q + r;
        const float v = silu_f(acc[r]);
        sact16[(size_t)row * IN_DIM + col0 + m] =
            (unsigned short)(pack_bf16x2(v, 0.0f) & 0xFFFFu);
    }
}

// fence helpers. Counted-wait safety rule (R3 post-mortem, R4/R5 validated):
// vmcnt(N) targeting cluster X requires N <= #STATICALLY-issued loads younger
// than X not yet provably retired. Dynamic loads (hash slow path) are legal
// anywhere but NEVER counted -> FIFO retirement only makes waits stricter.
#define SB0()    __builtin_amdgcn_sched_barrier(0)
#define LGKM0()  do { __asm__ __volatile__("s_waitcnt lgkmcnt(0)" ::: "memory"); SB0(); } while (0)
#define VMW(n)   do { __asm__ __volatile__("s_waitcnt vmcnt(" #n ")" ::: "memory"); SB0(); } while (0)

// ---------------------------------------------------------------------------
// k_edges_mfma (R8): blocks 0..4095  : edge tiles, 1 tile/wave, EIGHTH-staged
//                    X/Y double buffer (2 KB each) -> 4 KB/wave, 16 KB/block
//                    -> 8 blocks/CU (wave-cap) vs R5's 5: +60% TLP. Pipeline
//                    = 8 phases, 2-op stage clusters, VMW(2) counted waits.
//                    blocks 4096..4671: GEMM2 — atoms/latent = sact16@Wa^T+ba
// ---------------------------------------------------------------------------
__global__ __launch_bounds__(256, 8) void k_edges_mfma(const int* __restrict__ eidx,
                                                       const float* __restrict__ e,
                                                       const unsigned long long* __restrict__ tab,
                                                       const unsigned short* __restrict__ sact16,
                                                       const u32x4* __restrict__ A1pre,
                                                       const u32x4* __restrict__ A2pre,
                                                       const float* __restrict__ bbs,
                                                       const float* __restrict__ Wa,
                                                       const float* __restrict__ ba,
                                                       float* __restrict__ out) {
    __shared__ unsigned lds_all[4][1024];   // 4 KB/wave -> 16 KB/block
    const int blk  = blockIdx.x;
    const int lane = threadIdx.x & 63;
    const int wv   = threadIdx.x >> 6;
    const int m    = lane & 15;
    const int q    = lane >> 4;

    if (blk >= 4096) {
        // ---- GEMM2: wave -> (row_tile, col_tile) over 256 x 9 tiles
        const int wave = (blk - 4096) * 4 + wv;   // 0..2303
        const int rt = wave / 9;
        const int ct = wave - rt * 9;
        const int row0  = rt * 16;
        const int n_abs = ct * 16 + m;            // 0..143

        f32x4v acc;
        {
            const float bias = ba[n_abs];
            acc[0] = bias; acc[1] = bias; acc[2] = bias; acc[3] = bias;
        }

        const unsigned short* apu = sact16 + (size_t)(row0 + m) * IN_DIM + 8 * q;
        const float*          bp  = Wa + (size_t)n_abs * IN_DIM + 8 * q;

#pragma unroll
        for (int c8 = 0; c8 < 8; ++c8) {
            const bf16x8 A = *(const bf16x8*)(apu + 32 * c8);
            const float4 b0 = *(const float4*)(bp + 32 * c8);
            const float4 b1 = *(const float4*)(bp + 32 * c8 + 4);
            bf16x8 Bh, Bl;
            split_bf16(b0, b1, &Bh, &Bl);
            acc = __builtin_amdgcn_mfma_f32_16x16x32_bf16(A, Bh, acc, 0, 0, 0);
            acc = __builtin_amdgcn_mfma_f32_16x16x32_bf16(A, Bl, acc, 0, 0, 0);
        }
#pragma unroll
        for (int r = 0; r < 4; ++r) {
            const int row = row0 + 4 * q + r;
            if (n_abs < NAF)
                out[ATOMS_OFF + (size_t)row * NAF + n_abs] = acc[r];
            else
                out[LATENT_OFF + (size_t)row * LATENT + (n_abs - NAF)] = acc[r];
        }
        return;
    }

    // ---- edge tile: 1 tile (16 edges) per wave (R5 structure)
    const int k0 = __builtin_amdgcn_readfirstlane((blk * 4 + wv) * 16);
    unsigned* myl = lds_all[wv];
    const short one_q0 = (q == 0) ? (short)0x3F80 : (short)0;  // bf16(1.0)

    f32x4v acc_init;
#pragma unroll
    for (int r = 0; r < 4; ++r) {
        const int bond = 4 * q + r;
        acc_init[r] = (bond < NBT) ? bbs[bond] : 0.0f;
    }
    const u32x4* a1p = A1pre + lane;
    const u32x4* a2p = A2pre + lane;
    const int qh = q >> 1;
    const int qw = 2 * (q & 1);
    const int mw = m * 4;

    // -------- issue phase --------
    const unsigned j_m = (unsigned)eidx[k0 + m];
    const unsigned i_m = (unsigned)eidx[E_EDGES + k0 + m];

    const char* si_base = (const char*)(sact16 + (size_t)i_m * IN_DIM);  // 512 B rows
    const char* sj_base = (const char*)(sact16 + (size_t)j_m * IN_DIM);

    const unsigned keyF = (j_m << 12) | i_m, keyR = (i_m << 12) | j_m;
    const unsigned hF = hashh(keyF), hR = hashh(keyR);
    const unsigned long long sF0 = tab[hF];
    const unsigned long long sF1 = tab[(hF + 1u) & TMASK];
    const unsigned long long sR0 = tab[hR];
    const unsigned long long sR1 = tab[(hR + 1u) & TMASK];

    // eighth staging (SB0-pinned, 2 static ops): eighth p = bytes p*64..p*64+63
    // of each 512 B row. LDS: si 1 KB @ qb, sj 1 KB @ qb+1024.
    auto stage_e = [&](int p, int qb) {
        gld_lds16(si_base + p * 64 + q * 16, (char*)myl + qb);
        gld_lds16(sj_base + p * 64 + q * 16, (char*)myl + qb + 1024);
        SB0();
    };

    stage_e(0, 0);        // E0 -> X
    stage_e(1, 2048);     // E1 -> Y

    // -------- resolve (overlapped with staging flight) --------
    const int wf = resolve2(tab, keyF, sF0, sF1, hF);
    const int wr = resolve2(tab, keyR, sR0, sR1, hR);

    const float rsc = (wr >= 0) ? 0.5f : 0.0f;
    const int   wrc = (wr >= 0) ? wr : 0;
    const f32x4 ef = *(const f32x4*)(e + (size_t)wf  * EDGE_DIM + 4 * q);
    const f32x4 er = *(const f32x4*)(e + (size_t)wrc * EDGE_DIM + 4 * q);

    union { bf16x8 v; short s[8]; unsigned u[4]; } B1;
    {
        const f32x4 es = ef * 0.5f + er * rsc;
        B1.u[0] = pack_bf16x2(es[0], es[1]);
        B1.u[1] = pack_bf16x2(es[2], es[3]);
        B1.s[4] = one_q0; B1.s[5] = 0;
        B1.u[3] = 0u;
    }

    f32x4v acc0 = acc_init;
    f32x4v acc1 = {0.0f, 0.0f, 0.0f, 0.0f};

    // 2-group compute on one eighth-buffer at u32 offset qb4 (gbase even):
    // group g reads off = (2*(g&1)+qh)*64 + m*4 + 2*(q&1); sj at +256 u32.
    // (Index algebra verified against R5's quarter mapping: group g touches
    // only eighth g>>1 with exactly this intra-eighth offset.)
    auto qcompute2 = [&](int qb4, int gbase) {
#pragma unroll
        for (int gp = 0; gp < 2; ++gp) {
            const int g   = gbase + gp;
            const int off = (2 * gp + qh) * 64 + mw + qw;

            const u32x2 wi = *(const u32x2*)(myl + qb4 + off);
            const u32x2 wj = *(const u32x2*)(myl + qb4 + 256 + off);

            f32x4v C1;
            C1[0] = bf_lo(wi.x) + bf_lo(wj.x);
            C1[1] = bf_hi(wi.x) + bf_hi(wj.x);
            C1[2] = bf_lo(wi.y) + bf_lo(wj.y);
            C1[3] = bf_hi(wi.y) + bf_hi(wj.y);

            const u32x4 r1 = a1p[g * 64];
            const u32x4 r2 = a2p[g * 64];
            union { bf16x8 v; unsigned u[4]; } A1, A2;
            A1.u[0] = r1.x; A1.u[1] = r1.y; A1.u[2] = r1.z; A1.u[3] = 0u;
            A2.u[0] = r2.x; A2.u[1] = r2.y; A2.u[2] = 0u;   A2.u[3] = 0u;

            const f32x4v P = __builtin_amdgcn_mfma_f32_16x16x32_bf16(A1.v, B1.v, C1, 0, 0, 0);

            union { bf16x8 v; unsigned u[4]; } B2;
            B2.u[0] = pack_bf16x2(silu_f(P[0]), silu_f(P[1]));
            B2.u[1] = pack_bf16x2(silu_f(P[2]), silu_f(P[3]));
            B2.u[2] = 0u; B2.u[3] = 0u;

            if (gp & 1) acc1 = __builtin_amdgcn_mfma_f32_16x16x32_bf16(A2.v, B2.v, acc1, 0, 0, 0);
            else        acc0 = __builtin_amdgcn_mfma_f32_16x16x32_bf16(A2.v, B2.v, acc0, 0, 0, 0);
        }
    };

    // -------- 8-phase counted-vmcnt pipeline --------
    // B1's compiler wait on ef/er (youngest loads) already drains E0,E1 (FIFO);
    // explicit VMW(0) is the async-LDS fence (rule 21), timing-free here.
    VMW(0);
    qcompute2(0, 0);        // E0 @ X
    LGKM0(); stage_e(2, 0);        // E2 -> X

    qcompute2(512, 2);      // E1 @ Y (covered by VMW(0))
    LGKM0(); stage_e(3, 2048);     // E3 -> Y

    VMW(2);                 // E2 done (outstanding: E2+E3=4 -> leave E3's 2)
    qcompute2(0, 4);        // E2 @ X
    LGKM0(); stage_e(4, 0);        // E4 -> X

    VMW(2);                 // E3 done (outstanding: E3+E4)
    qcompute2(512, 6);      // E3 @ Y
    LGKM0(); stage_e(5, 2048);     // E5 -> Y

    VMW(2);                 // E4 done
    qcompute2(0, 8);        // E4 @ X
    LGKM0(); stage_e(6, 0);        // E6 -> X

    VMW(2);                 // E5 done
    qcompute2(512, 10);     // E5 @ Y
    LGKM0(); stage_e(7, 2048);     // E7 -> Y

    VMW(2);                 // E6 done (outstanding: E6+E7)
    qcompute2(0, 12);       // E6 @ X

    VMW(0);                 // E7 done
    qcompute2(512, 14);     // E7 @ Y

    // -------- store bonds --------
    const f32x4v accT = acc0 + acc1;
    float* op = out + BONDS_OFF + (size_t)(k0 + m) * NBT;
    if (q == 0) {
        __builtin_nontemporal_store(accT[0], op + 0);
        __builtin_nontemporal_store(accT[1], op + 1);
        __builtin_nontemporal_store(accT[2], op + 2);
        __builtin_nontemporal_store(accT[3], op + 3);
    } else if (q == 1) {
        __builtin_nontemporal_store(accT[0], op + 4);
    }
}

// ---------------------------------------------------------------------------
extern "C" void kernel_launch(void* const* d_in, const int* in_sizes, int n_in,
                              void* d_out, int out_size, void* d_ws, size_t ws_size,
                              hipStream_t stream) {
    const float* s   = (const float*)d_in[0];
    const float* e   = (const float*)d_in[1];
    const int*   eix = (const int*)d_in[3];
    const float* Wsh = (const float*)d_in[4];
    const float* bsh = (const float*)d_in[5];
    const float* Wb  = (const float*)d_in[6];
    const float* bbo = (const float*)d_in[7];
    const float* Wbs = (const float*)d_in[8];
    const float* bbs = (const float*)d_in[9];
    const float* Wa  = (const float*)d_in[10];
    const float* ba  = (const float*)d_in[11];
    float* out = (float*)d_out;

    char* ws = (char*)d_ws;
    unsigned short*     sact16 = (unsigned short*)ws;             // 2 MB @ 0
    u32x4*              A1pre  = (u32x4*)(ws + (2u << 20));       // 16 KB
    u32x4*              A2pre  = (u32x4*)(ws + (2u << 20) + 16384);
    unsigned long long* tab    = (unsigned long long*)(ws + (3u << 20)); // 8 MB

    (void)hipMemsetAsync(tab, 0x00, TSIZE * sizeof(unsigned long long), stream);

    k_front<<<2049, 256, 0, stream>>>(s, Wsh, bsh, eix, Wb, bbo, Wbs,
                                      sact16, tab, A1pre, A2pre);
    k_edges_mfma<<<4672, 256, 0, stream>>>(eix, e, tab, sact16,
                                           A1pre, A2pre, bbs, Wa, ba, out);
}

// Round 9
// 174.763 us; speedup vs baseline: 1.2495x; 1.0021x over previous
//
#include <hip/hip_runtime.h>
#include <hip/hip_bf16.h>

#define N_NODES   4096
#define E_EDGES   262144
#define IN_DIM    256
#define EDGE_DIM  16
#define NAF       16
#define LATENT    128
#define NBT       5

#define LATENT_OFF 0
#define ATOMS_OFF  (N_NODES * LATENT)                 // 524288
#define BONDS_OFF  (ATOMS_OFF + N_NODES * NAF)        // 589824

// hash table: 2^20 u64 slots = 8 MB, load factor 0.25
#define TBITS 20
#define TSIZE (1u << TBITS)
#define TMASK (TSIZE - 1u)

typedef float    f32x4  __attribute__((ext_vector_type(4)));
typedef float    f32x4v __attribute__((ext_vector_type(4)));
typedef short    bf16x8 __attribute__((ext_vector_type(8)));
typedef unsigned u32x2  __attribute__((ext_vector_type(2)));
typedef unsigned u32x4  __attribute__((ext_vector_type(4)));

// silu via v_rcp_f32 (accuracy validated in R1: absmax unchanged)
__device__ __forceinline__ float silu_f(float x) {
    return x * __builtin_amdgcn_rcpf(1.0f + __expf(-x));
}

__device__ __forceinline__ unsigned pack_bf16x2(float lo, float hi) {
#if __has_builtin(__builtin_amdgcn_cvt_pk_bf16_f32)
    typedef __bf16 bf16x2_t __attribute__((ext_vector_type(2)));
    union { bf16x2_t v; unsigned u; } c;
    c.v = __builtin_amdgcn_cvt_pk_bf16_f32(lo, hi);
    return c.u;
#else
    union { float f; unsigned u; } a, b;
    a.f = lo; b.f = hi;
    const unsigned ra = (a.u + 0x7FFFu + ((a.u >> 16) & 1u)) >> 16;
    const unsigned rb = (b.u + 0x7FFFu + ((b.u >> 16) & 1u)) >> 16;
    return ra | (rb << 16);
#endif
}

__device__ __forceinline__ float bf_lo(unsigned u) {
    union { unsigned x; float f; } c; c.x = u << 16; return c.f;
}
__device__ __forceinline__ float bf_hi(unsigned u) {
    union { unsigned x; float f; } c; c.x = u & 0xFFFF0000u; return c.f;
}

// split fp32x8 into bf16 hi + bf16 lo fragments (x = hi + lo exactly to 2^-18)
__device__ __forceinline__ void split_bf16(const float4 x0, const float4 x1,
                                           bf16x8* hi, bf16x8* lo) {
    union { bf16x8 v; unsigned u[4]; } H, L;
    H.u[0] = pack_bf16x2(x0.x, x0.y);
    H.u[1] = pack_bf16x2(x0.z, x0.w);
    H.u[2] = pack_bf16x2(x1.x, x1.y);
    H.u[3] = pack_bf16x2(x1.z, x1.w);
    L.u[0] = pack_bf16x2(x0.x - bf_lo(H.u[0]), x0.y - bf_hi(H.u[0]));
    L.u[1] = pack_bf16x2(x0.z - bf_lo(H.u[1]), x0.w - bf_hi(H.u[1]));
    L.u[2] = pack_bf16x2(x1.x - bf_lo(H.u[2]), x1.y - bf_hi(H.u[2]));
    L.u[3] = pack_bf16x2(x1.z - bf_lo(H.u[3]), x1.w - bf_hi(H.u[3]));
    *hi = H.v; *lo = L.v;
}

// async gather: per-lane 16B global -> LDS[uniform base + lane*16]
__device__ __forceinline__ void gld_lds16(const void* g, void* l) {
    __builtin_amdgcn_global_load_lds(
        (const __attribute__((address_space(1))) unsigned*)g,
        (__attribute__((address_space(3))) unsigned*)l, 16, 0, 0);
}

__device__ __forceinline__ unsigned hashh(unsigned key) {
    return (key * 2654435761u) >> (32 - TBITS);
}

// 2-slot speculative resolve (R5, validated). Slow-path loads are dynamic but
// never counted in any vmcnt N -> only ever make counted waits stricter.
__device__ __forceinline__ int resolve2(const unsigned long long* __restrict__ tab,
                                        unsigned key, unsigned long long s0,
                                        unsigned long long s1, unsigned h) {
    if ((unsigned)(s0 >> 18) == key + 1u) return (int)(s0 & 0x3FFFFu);
    if (s0 == 0ULL) return -1;
    if ((unsigned)(s1 >> 18) == key + 1u) return (int)(s1 & 0x3FFFFu);
    if (s1 == 0ULL) return -1;
    h = (h + 2u) & TMASK;
    while (true) {
        const unsigned long long cur = tab[h];
        if (cur == 0ULL) return -1;
        if ((unsigned)(cur >> 18) == key + 1u) return (int)(cur & 0x3FFFFu);
        h = (h + 1u) & TMASK;
    }
}

// ---------------------------------------------------------------------------
// k_front: blocks 0..1023  : GEMM1
//          blocks 1024..2047: hash insert (direct-CAS, validated R6/R7)
//          block  2048      : prepack A1pre/A2pre
// ---------------------------------------------------------------------------
__global__ __launch_bounds__(256) void k_front(const float* __restrict__ s,
                                               const float* __restrict__ Wsh,
                                               const float* __restrict__ bsh,
                                               const int* __restrict__ eidx,
                                               const float* __restrict__ Wb,
                                               const float* __restrict__ bb,
                                               const float* __restrict__ Wbs,
                                               unsigned short* __restrict__ sact16,
                                               unsigned long long* __restrict__ tab,
                                               u32x4* __restrict__ A1pre,
                                               u32x4* __restrict__ A2pre) {
    const int blk = blockIdx.x;
    const int c   = threadIdx.x;

    if (blk >= 1024) {
        if (blk < 2048) {
            // ---- hash insert (winner = max edge id per key), direct CAS
            const int k = (blk - 1024) * 256 + c;
            const unsigned j = (unsigned)eidx[k];
            const unsigned i = (unsigned)eidx[E_EDGES + k];
            const unsigned key = (j << 12) | i;
            const unsigned long long mine =
                ((unsigned long long)(key + 1u) << 18) | (unsigned)k;
            unsigned h = hashh(key);
            while (true) {
                const unsigned long long old = atomicCAS(&tab[h], 0ULL, mine);
                if (old == 0ULL) return;                    // claimed empty slot
                if ((unsigned)(old >> 18) == key + 1u) {    // key already present
                    atomicMax(&tab[h], mine);
                    return;
                }
                h = (h + 1u) & TMASK;
            }
        } else {
            // ---- prepack: A1 = {Wb pair x2, pk(bb,0), 0}; A2 = {Wbs pair x2, 0, 0}
#pragma unroll
            for (int ee = 0; ee < 4; ++ee) {
                const int idx  = c + 256 * ee;
                const int g    = idx >> 6;
                const int lane = idx & 63;
                const int mm   = lane & 15;
                const int qq   = lane >> 4;

                const float4 w = *(const float4*)(Wb + (16 * g + mm) * EDGE_DIM + 4 * qq);
                u32x4 r1;
                r1.x = pack_bf16x2(w.x, w.y);
                r1.y = pack_bf16x2(w.z, w.w);
                r1.z = pack_bf16x2(bb[16 * g + mm], 0.0f);
                r1.w = 0u;
                A1pre[idx] = r1;

                u32x4 r2;
                if (mm < NBT) {
                    const float4 ws = *(const float4*)(Wbs + mm * IN_DIM + 16 * g + 4 * qq);
                    r2.x = pack_bf16x2(ws.x, ws.y);
                    r2.y = pack_bf16x2(ws.z, ws.w);
                } else {
                    r2.x = 0u; r2.y = 0u;
                }
                r2.z = 0u; r2.w = 0u;
                A2pre[idx] = r2;
            }
        }
        return;
    }

    // ---- GEMM1 tile: wave -> (row_tile, col_tile); 256 x 16 tiles
    const int lane = c & 63;
    const int wv   = c >> 6;
    const int wave = blk * 4 + wv;
    const int m    = lane & 15;
    const int q    = lane >> 4;
    const int row0 = (wave >> 4) * 16;
    const int col0 = (wave & 15) * 16;

    f32x4v acc;
    {
        const float bias = bsh[col0 + m];
        acc[0] = bias; acc[1] = bias; acc[2] = bias; acc[3] = bias;
    }

    const float* ap = s   + (size_t)(row0 + m) * IN_DIM + 8 * q;
    const float* bp = Wsh + (size_t)(col0 + m) * IN_DIM + 8 * q;

#pragma unroll
    for (int c8 = 0; c8 < 8; ++c8) {
        const float4 a0 = *(const float4*)(ap + 32 * c8);
        const float4 a1 = *(const float4*)(ap + 32 * c8 + 4);
        const float4 b0 = *(const float4*)(bp + 32 * c8);
        const float4 b1 = *(const float4*)(bp + 32 * c8 + 4);
        bf16x8 Ah, Al, Bh, Bl;
        split_bf16(a0, a1, &Ah, &Al);
        split_bf16(b0, b1, &Bh, &Bl);
        acc = __builtin_amdgcn_mfma_f32_16x16x32_bf16(Ah, Bh, acc, 0, 0, 0);
        acc = __builtin_amdgcn_mfma_f32_16x16x32_bf16(Al, Bh, acc, 0, 0, 0);
        acc = __builtin_amdgcn_mfma_f32_16x16x32_bf16(Ah, Bl, acc, 0, 0, 0);
    }

#pragma unroll
    for (int r = 0; r < 4; ++r) {
        const int row = row0 + 4 * q + r;
        const float v = silu_f(acc[r]);
        sact16[(size_t)row * IN_DIM + col0 + m] =
            (unsigned short)(pack_bf16x2(v, 0.0f) & 0xFFFFu);
    }
}

// fence helpers. Counted-wait safety rule (R3 post-mortem, R4/R5/R8 validated):
// vmcnt(N) targeting cluster X requires N <= #STATICALLY-issued loads younger
// than X not yet provably retired. Dynamic loads (hash slow path) are legal
// anywhere but NEVER counted -> FIFO retirement only makes waits stricter.
#define SB0()    __builtin_amdgcn_sched_barrier(0)
#define LGKM0()  do { __asm__ __volatile__("s_waitcnt lgkmcnt(0)" ::: "memory"); SB0(); } while (0)
#define VMW(n)   do { __asm__ __volatile__("s_waitcnt vmcnt(" #n ")" ::: "memory"); SB0(); } while (0)

// ---------------------------------------------------------------------------
// k_edges_mfma (R9): blocks 0..4095  : edge tiles, 1 tile/wave, eighth-staged
//   TRIPLE buffer (depth 3): prefetch distance = 2 phases x ~220 cyc >= ~400
//   cyc loaded gather latency (R8 post-mortem: depth 2 exposed ~200 cyc/phase,
//   cancelling the TLP gain). 6 KB/wave -> 24 KB/block -> 6 blocks/CU.
//   blocks 4096..4671: GEMM2 — atoms/latent = sact16@Wa^T + ba
// ---------------------------------------------------------------------------
__global__ __launch_bounds__(256, 6) void k_edges_mfma(const int* __restrict__ eidx,
                                                       const float* __restrict__ e,
                                                       const unsigned long long* __restrict__ tab,
                                                       const unsigned short* __restrict__ sact16,
                                                       const u32x4* __restrict__ A1pre,
                                                       const u32x4* __restrict__ A2pre,
                                                       const float* __restrict__ bbs,
                                                       const float* __restrict__ Wa,
                                                       const float* __restrict__ ba,
                                                       float* __restrict__ out) {
    __shared__ unsigned lds_all[4][1536];   // 6 KB/wave -> 24 KB/block
    const int blk  = blockIdx.x;
    const int lane = threadIdx.x & 63;
    const int wv   = threadIdx.x >> 6;
    const int m    = lane & 15;
    const int q    = lane >> 4;

    if (blk >= 4096) {
        // ---- GEMM2: wave -> (row_tile, col_tile) over 256 x 9 tiles
        const int wave = (blk - 4096) * 4 + wv;   // 0..2303
        const int rt = wave / 9;
        const int ct = wave - rt * 9;
        const int row0  = rt * 16;
        const int n_abs = ct * 16 + m;            // 0..143

        f32x4v acc;
        {
            const float bias = ba[n_abs];
            acc[0] = bias; acc[1] = bias; acc[2] = bias; acc[3] = bias;
        }

        const unsigned short* apu = sact16 + (size_t)(row0 + m) * IN_DIM + 8 * q;
        const float*          bp  = Wa + (size_t)n_abs * IN_DIM + 8 * q;

#pragma unroll
        for (int c8 = 0; c8 < 8; ++c8) {
            const bf16x8 A = *(const bf16x8*)(apu + 32 * c8);
            const float4 b0 = *(const float4*)(bp + 32 * c8);
            const float4 b1 = *(const float4*)(bp + 32 * c8 + 4);
            bf16x8 Bh, Bl;
            split_bf16(b0, b1, &Bh, &Bl);
            acc = __builtin_amdgcn_mfma_f32_16x16x32_bf16(A, Bh, acc, 0, 0, 0);
            acc = __builtin_amdgcn_mfma_f32_16x16x32_bf16(A, Bl, acc, 0, 0, 0);
        }
#pragma unroll
        for (int r = 0; r < 4; ++r) {
            const int row = row0 + 4 * q + r;
            if (n_abs < NAF)
                out[ATOMS_OFF + (size_t)row * NAF + n_abs] = acc[r];
            else
                out[LATENT_OFF + (size_t)row * LATENT + (n_abs - NAF)] = acc[r];
        }
        return;
    }

    // ---- edge tile: 1 tile (16 edges) per wave
    const int k0 = __builtin_amdgcn_readfirstlane((blk * 4 + wv) * 16);
    unsigned* myl = lds_all[wv];
    const short one_q0 = (q == 0) ? (short)0x3F80 : (short)0;  // bf16(1.0)

    f32x4v acc_init;
#pragma unroll
    for (int r = 0; r < 4; ++r) {
        const int bond = 4 * q + r;
        acc_init[r] = (bond < NBT) ? bbs[bond] : 0.0f;
    }
    const u32x4* a1p = A1pre + lane;
    const u32x4* a2p = A2pre + lane;
    const int qh = q >> 1;
    const int qw = 2 * (q & 1);
    const int mw = m * 4;

    // -------- issue phase --------
    const unsigned j_m = (unsigned)eidx[k0 + m];
    const unsigned i_m = (unsigned)eidx[E_EDGES + k0 + m];

    const char* si_base = (const char*)(sact16 + (size_t)i_m * IN_DIM);  // 512 B rows
    const char* sj_base = (const char*)(sact16 + (size_t)j_m * IN_DIM);

    const unsigned keyF = (j_m << 12) | i_m, keyR = (i_m << 12) | j_m;
    const unsigned hF = hashh(keyF), hR = hashh(keyR);
    const unsigned long long sF0 = tab[hF];
    const unsigned long long sF1 = tab[(hF + 1u) & TMASK];
    const unsigned long long sR0 = tab[hR];
    const unsigned long long sR1 = tab[(hR + 1u) & TMASK];

    // eighth staging (SB0-pinned, 2 static ops): eighth p = bytes p*64..p*64+63
    // of each 512 B row. Buffer at byte qb: si 1 KB @ qb, sj 1 KB @ qb+1024.
    auto stage_e = [&](int p, int qb) {
        gld_lds16(si_base + p * 64 + q * 16, (char*)myl + qb);
        gld_lds16(sj_base + p * 64 + q * 16, (char*)myl + qb + 1024);
        SB0();
    };

    stage_e(0, 0);        // E0 -> buf0
    stage_e(1, 2048);     // E1 -> buf1
    stage_e(2, 4096);     // E2 -> buf2

    // -------- resolve (overlapped with staging flight) --------
    const int wf = resolve2(tab, keyF, sF0, sF1, hF);
    const int wr = resolve2(tab, keyR, sR0, sR1, hR);

    const float rsc = (wr >= 0) ? 0.5f : 0.0f;
    const int   wrc = (wr >= 0) ? wr : 0;
    const f32x4 ef = *(const f32x4*)(e + (size_t)wf  * EDGE_DIM + 4 * q);
    const f32x4 er = *(const f32x4*)(e + (size_t)wrc * EDGE_DIM + 4 * q);

    union { bf16x8 v; short s[8]; unsigned u[4]; } B1;
    {
        const f32x4 es = ef * 0.5f + er * rsc;
        B1.u[0] = pack_bf16x2(es[0], es[1]);
        B1.u[1] = pack_bf16x2(es[2], es[3]);
        B1.s[4] = one_q0; B1.s[5] = 0;
        B1.u[3] = 0u;
    }

    f32x4v acc0 = acc_init;
    f32x4v acc1 = {0.0f, 0.0f, 0.0f, 0.0f};

    // 2-group compute on one eighth-buffer at u32 offset qb4 (gbase = 2p):
    // group g reads off = (2*(g&1)+qh)*64 + m*4 + 2*(q&1); sj at +256 u32.
    auto qcompute2 = [&](int qb4, int gbase) {
#pragma unroll
        for (int gp = 0; gp < 2; ++gp) {
            const int g   = gbase + gp;
            const int off = (2 * gp + qh) * 64 + mw + qw;

            const u32x2 wi = *(const u32x2*)(myl + qb4 + off);
            const u32x2 wj = *(const u32x2*)(myl + qb4 + 256 + off);

            f32x4v C1;
            C1[0] = bf_lo(wi.x) + bf_lo(wj.x);
            C1[1] = bf_hi(wi.x) + bf_hi(wj.x);
            C1[2] = bf_lo(wi.y) + bf_lo(wj.y);
            C1[3] = bf_hi(wi.y) + bf_hi(wj.y);

            const u32x4 r1 = a1p[g * 64];
            const u32x4 r2 = a2p[g * 64];
            union { bf16x8 v; unsigned u[4]; } A1, A2;
            A1.u[0] = r1.x; A1.u[1] = r1.y; A1.u[2] = r1.z; A1.u[3] = 0u;
            A2.u[0] = r2.x; A2.u[1] = r2.y; A2.u[2] = 0u;   A2.u[3] = 0u;

            const f32x4v P = __builtin_amdgcn_mfma_f32_16x16x32_bf16(A1.v, B1.v, C1, 0, 0, 0);

            union { bf16x8 v; unsigned u[4]; } B2;
            B2.u[0] = pack_bf16x2(silu_f(P[0]), silu_f(P[1]));
            B2.u[1] = pack_bf16x2(silu_f(P[2]), silu_f(P[3]));
            B2.u[2] = 0u; B2.u[3] = 0u;

            if (gp & 1) acc1 = __builtin_amdgcn_mfma_f32_16x16x32_bf16(A2.v, B2.v, acc1, 0, 0, 0);
            else        acc0 = __builtin_amdgcn_mfma_f32_16x16x32_bf16(A2.v, B2.v, acc0, 0, 0, 0);
        }
    };

    // -------- 8-phase depth-3 counted-vmcnt pipeline --------
    // B1's compiler wait on ef/er (youngest loads) drains E0-E2 (FIFO);
    // explicit VMW(0) is the async-LDS fence (rule 21), timing-free here.
    VMW(0);
    qcompute2(0, 0);        // E0 @ buf0
    LGKM0(); stage_e(3, 0);        // E3 -> buf0

    VMW(2);                 // free: E1 already drained; <= {E3} outstanding
    qcompute2(512, 2);      // E1 @ buf1
    LGKM0(); stage_e(4, 2048);     // E4 -> buf1

    VMW(4);                 // free: E2 drained; <= {E3,E4} outstanding
    qcompute2(1024, 4);     // E2 @ buf2
    LGKM0(); stage_e(5, 4096);     // E5 -> buf2

    VMW(4);                 // E3 done (younger static: E4,E5 = 4; issued 3 phases ago)
    qcompute2(0, 6);        // E3 @ buf0
    LGKM0(); stage_e(6, 0);        // E6 -> buf0

    VMW(4);                 // E4 done (younger static: E5,E6 = 4)
    qcompute2(512, 8);      // E4 @ buf1
    LGKM0(); stage_e(7, 2048);     // E7 -> buf1

    VMW(4);                 // E5 done (younger static: E6,E7 = 4)
    qcompute2(1024, 10);    // E5 @ buf2

    VMW(2);                 // E6 done (younger static: E7 = 2)
    qcompute2(0, 12);       // E6 @ buf0

    VMW(0);                 // E7 done
    qcompute2(512, 14);     // E7 @ buf1

    // -------- store bonds (plain stores: test write-combining vs R8's 18 MB) --------
    const f32x4v accT = acc0 + acc1;
    float* op = out + BONDS_OFF + (size_t)(k0 + m) * NBT;
    if (q == 0) {
        op[0] = accT[0];
        op[1] = accT[1];
        op[2] = accT[2];
        op[3] = accT[3];
    } else if (q == 1) {
        op[4] = accT[0];
    }
}

// ---------------------------------------------------------------------------
extern "C" void kernel_launch(void* const* d_in, const int* in_sizes, int n_in,
                              void* d_out, int out_size, void* d_ws, size_t ws_size,
                              hipStream_t stream) {
    const float* s   = (const float*)d_in[0];
    const float* e   = (const float*)d_in[1];
    const int*   eix = (const int*)d_in[3];
    const float* Wsh = (const float*)d_in[4];
    const float* bsh = (const float*)d_in[5];
    const float* Wb  = (const float*)d_in[6];
    const float* bbo = (const float*)d_in[7];
    const float* Wbs = (const float*)d_in[8];
    const float* bbs = (const float*)d_in[9];
    const float* Wa  = (const float*)d_in[10];
    const float* ba  = (const float*)d_in[11];
    float* out = (float*)d_out;

    char* ws = (char*)d_ws;
    unsigned short*     sact16 = (unsigned short*)ws;             // 2 MB @ 0
    u32x4*              A1pre  = (u32x4*)(ws + (2u << 20));       // 16 KB
    u32x4*              A2pre  = (u32x4*)(ws + (2u << 20) + 16384);
    unsigned long long* tab    = (unsigned long long*)(ws + (3u << 20)); // 8 MB

    (void)hipMemsetAsync(tab, 0x00, TSIZE * sizeof(unsigned long long), stream);

    k_front<<<2049, 256, 0, stream>>>(s, Wsh, bsh, eix, Wb, bbo, Wbs,
                                      sact16, tab, A1pre, A2pre);
    k_edges_mfma<<<4672, 256, 0, stream>>>(eix, e, tab, sact16,
                                           A1pre, A2pre, bbs, Wa, ba, out);
}